// Round 3
// baseline (292.793 us; speedup 1.0000x reference)
//
#include <hip/hip_runtime.h>
#include <hip/hip_bf16.h>
#include <math.h>

#define LN_EPS 1e-5f

typedef __attribute__((ext_vector_type(4))) float f4_t;
typedef __attribute__((ext_vector_type(8))) short bf8_t;

__device__ __forceinline__ unsigned short f2bf(float x) {
    unsigned u = __builtin_bit_cast(unsigned, x);
    unsigned r = (u + 0x7FFFu + ((u >> 16) & 1u)) >> 16;
    return (unsigned short)r;
}
__device__ __forceinline__ float bf2f(unsigned short u) {
    return __builtin_bit_cast(float, ((unsigned)u) << 16);
}

// ---------------- kernel 1: reorder W1/W2 into MFMA-fragment-major bf16 -------
// W1f frag (ftile 0..63, kb 0..7): lane l holds W1[ftile*16+(l&15)][kb*32+(l>>4)*8 ..+8]
// W2f frag (ctile 0..15, kt 0..31): lane l holds W2[ctile*16+(l&15)][kt*32+(l>>4)*8 ..+8]
__global__ void cvt_kernel(const float* __restrict__ W1, const float* __restrict__ W2,
                           bf8_t* __restrict__ W1f, bf8_t* __restrict__ W2f) {
    int gid = blockIdx.x * 256 + threadIdx.x;   // 0..65535
    union { bf8_t v; unsigned short u[8]; } pk;
    if (gid < 32768) {
        int lane = gid & 63;
        int f = (gid >> 9) * 16 + (lane & 15);
        int k = ((gid >> 6) & 7) * 32 + (lane >> 4) * 8;
        const float* src = W1 + (size_t)f * 256 + k;
#pragma unroll
        for (int e = 0; e < 8; ++e) pk.u[e] = f2bf(src[e]);
        W1f[gid] = pk.v;
    } else {
        int g = gid - 32768;
        int lane = g & 63;
        int c = (g >> 11) * 16 + (lane & 15);
        int k = ((g >> 6) & 31) * 32 + (lane >> 4) * 8;
        const float* src = W2 + (size_t)c * 1024 + k;
#pragma unroll
        for (int e = 0; e < 8; ++e) pk.u[e] = f2bf(src[e]);
        W2f[g] = pk.v;
    }
}

// ---------------- kernel 2: 4x4 block pool: fs[n][k][c] ------------------------
__global__ void pool_kernel(const float* __restrict__ feature, float* __restrict__ fs) {
    int bk = blockIdx.x;           // n*400 + k
    int n = bk / 400, k = bk % 400;
    int c = threadIdx.x;
    int h = k / 20, w = k % 20;
    const float* base = feature + ((size_t)(n * 256 + c)) * 6400 + (h * 4) * 80 + w * 4;
    float s = 0.f;
#pragma unroll
    for (int dh = 0; dh < 4; ++dh) {
        float4 v = *reinterpret_cast<const float4*>(base + dh * 80);
        s += v.x + v.y + v.z + v.w;
    }
    fs[((size_t)n * 400 + k) * 256 + c] = s;
}

// ---------------- kernel 3: r[n][i][c] = sum_k weight[n][i][k] * fs[n][k][c] ---
// 16 output rows per block, 200 blocks.
__global__ void att_kernel(const float* __restrict__ wgt, const float* __restrict__ fs,
                           float* __restrict__ r) {
    __shared__ float fsl[16][256];
    __shared__ float wl[16][16];
    int b = blockIdx.x;
    int n = b / 25, i0 = (b % 25) * 16;
    int tid = threadIdx.x;
    const float* wbase = wgt + (size_t)n * 400 * 400;
    const float* fsbase = fs + (size_t)n * 400 * 256;
    float acc[16];
#pragma unroll
    for (int ii = 0; ii < 16; ++ii) acc[ii] = 0.f;
    for (int k0 = 0; k0 < 400; k0 += 16) {
#pragma unroll
        for (int jj = 0; jj < 16; ++jj)
            fsl[jj][tid] = fsbase[(size_t)(k0 + jj) * 256 + tid];
        wl[tid >> 4][tid & 15] = wbase[(size_t)(i0 + (tid >> 4)) * 400 + k0 + (tid & 15)];
        __syncthreads();
#pragma unroll
        for (int kk = 0; kk < 16; ++kk) {
            float f = fsl[kk][tid];
#pragma unroll
            for (int ii = 0; ii < 16; ++ii) acc[ii] += wl[ii][kk] * f;
        }
        __syncthreads();
    }
#pragma unroll
    for (int ii = 0; ii < 16; ++ii)
        r[((size_t)n * 400 + i0 + ii) * 256 + tid] = acc[ii];
}

// ---------------- kernel 4: fused residual+att + LN1 + MLP(GELU) + LN2 ---------
// 64 tokens/block, 512 threads = 8 waves. Wave q: GEMM1 f-tile fc*8+q,
// GEMM2 c-tiles {2q,2q+1}. B-fragments batched 8-deep for vmcnt amortization.
__global__ __launch_bounds__(512, 4) void main_kernel(
    const float* __restrict__ feat, const float* __restrict__ r,
    const float* __restrict__ ln1g, const float* __restrict__ ln1b,
    const bf8_t* __restrict__ W1f, const float* __restrict__ b1,
    const bf8_t* __restrict__ W2f, const float* __restrict__ b2,
    const float* __restrict__ ln2g, const float* __restrict__ ln2b,
    float* __restrict__ out) {
    __shared__ unsigned short xt[64 * 256];   // [t][c] swizzled, 32 KB
    __shared__ unsigned short ht[64 * 128];   // [t][f] swizzled, 16 KB
    __shared__ float psum[8][64], psq[8][64];
    __shared__ float stat[2][64];

    int bid = blockIdx.x;
    int n = bid / 100;
    int p0 = (bid % 100) * 64;
    int tid = threadIdx.x;
    int lane = tid & 63;
    int q = tid >> 6;                     // wave id 0..7
    int t = lane;                         // token row this thread loads in phase 1
    int p = p0 + t;
    int iatt = ((p / 80) >> 2) * 20 + ((p % 80) >> 2);

    // ---- phase 1: x = residual + att, LN1. Thread covers 32 channels of token t.
    const float* fbase = feat + ((size_t)(n * 256 + q * 32)) * 6400 + p;
    const float* rrow = r + ((size_t)(n * 400 + iatt)) * 256 + q * 32;
    float xv[32];
    float s1 = 0.f, s2 = 0.f;
#pragma unroll
    for (int j = 0; j < 32; ++j) {
        float v = fbase[(size_t)j * 6400] + rrow[j];
        xv[j] = v;
        s1 += v;
        s2 += v * v;
    }
    psum[q][t] = s1;
    psq[q][t] = s2;
    __syncthreads();
    if (tid < 64) {
        float a = 0.f, b = 0.f;
#pragma unroll
        for (int qq = 0; qq < 8; ++qq) { a += psum[qq][tid]; b += psq[qq][tid]; }
        float mu = a * (1.f / 256.f);
        float var = b * (1.f / 256.f) - mu * mu;
        stat[0][tid] = mu;
        stat[1][tid] = rsqrtf(var + LN_EPS);
    }
    __syncthreads();
    float mu = stat[0][t], rs = stat[1][t];
#pragma unroll
    for (int jj = 0; jj < 4; ++jj) {
        union { bf8_t v; unsigned short u[8]; } pk;
#pragma unroll
        for (int e = 0; e < 8; ++e) {
            int c = q * 32 + jj * 8 + e;
            float y = (xv[jj * 8 + e] - mu) * rs * ln1g[c] + ln1b[c];
            pk.u[e] = f2bf(y);
        }
        int byte = t * 512 + ((q * 64 + jj * 16) ^ ((t & 7) << 4));
        *reinterpret_cast<bf8_t*>(reinterpret_cast<char*>(xt) + byte) = pk.v;
    }
    __syncthreads();

    // ---- MFMA phase ----
    int lm = lane & 15, lk = lane >> 4;
    const char* xtb = reinterpret_cast<const char*>(xt);
    const char* htb = reinterpret_cast<const char*>(ht);
    char* htw = reinterpret_cast<char*>(ht);

    f4_t oacc[8];   // [m][ctl] : 4 m-tiles x 2 c-tiles
#pragma unroll
    for (int i = 0; i < 8; ++i) oacc[i] = (f4_t){0.f, 0.f, 0.f, 0.f};

    for (int fc = 0; fc < 8; ++fc) {
        // GEMM1: wave q owns f-tile fc*8+q. Batch all 8 B-frags first.
        const bf8_t* w1p = W1f + (size_t)(fc * 8 + q) * 8 * 64 + lane;
        bf8_t bfr[8];
#pragma unroll
        for (int kb = 0; kb < 8; ++kb) bfr[kb] = w1p[kb * 64];
        f4_t hacc[4];
#pragma unroll
        for (int i = 0; i < 4; ++i) hacc[i] = (f4_t){0.f, 0.f, 0.f, 0.f};
#pragma unroll
        for (int kb = 0; kb < 8; ++kb) {
#pragma unroll
            for (int m = 0; m < 4; ++m) {
                int row = m * 16 + lm;
                bf8_t a = *reinterpret_cast<const bf8_t*>(
                    xtb + row * 512 + ((kb * 64 + lk * 16) ^ ((row & 7) << 4)));
                hacc[m] = __builtin_amdgcn_mfma_f32_16x16x32_bf16(a, bfr[kb], hacc[m], 0, 0, 0);
            }
        }
        __syncthreads();   // previous fc's GEMM2 reads of ht are done
        // bias + exact GELU -> swizzled ht (wave q writes cols q*16..q*16+15)
        {
            int fl = q * 16 + lm;
            float bias = b1[fc * 128 + fl];
#pragma unroll
            for (int m = 0; m < 4; ++m) {
#pragma unroll
                for (int j = 0; j < 4; ++j) {
                    int row = m * 16 + lk * 4 + j;
                    float hv = hacc[m][j] + bias;
                    float g = 0.5f * hv * (1.f + erff(hv * 0.70710678f));
                    *reinterpret_cast<unsigned short*>(
                        htw + row * 256 + ((fl * 2) ^ ((row & 7) << 4))) = f2bf(g);
                }
            }
        }
        __syncthreads();
        // GEMM2: wave q owns c-tiles {2q, 2q+1}; k-tiles fc*4..fc*4+3.
        bf8_t b2r[8];
#pragma unroll
        for (int kb = 0; kb < 4; ++kb) {
#pragma unroll
            for (int ctl = 0; ctl < 2; ++ctl)
                b2r[kb * 2 + ctl] =
                    W2f[(size_t)((2 * q + ctl) * 32 + fc * 4 + kb) * 64 + lane];
        }
#pragma unroll
        for (int kb = 0; kb < 4; ++kb) {
#pragma unroll
            for (int m = 0; m < 4; ++m) {
                int row = m * 16 + lm;
                bf8_t a = *reinterpret_cast<const bf8_t*>(
                    htb + row * 256 + ((kb * 64 + lk * 16) ^ ((row & 7) << 4)));
                oacc[m * 2 + 0] = __builtin_amdgcn_mfma_f32_16x16x32_bf16(a, b2r[kb * 2 + 0], oacc[m * 2 + 0], 0, 0, 0);
                oacc[m * 2 + 1] = __builtin_amdgcn_mfma_f32_16x16x32_bf16(a, b2r[kb * 2 + 1], oacc[m * 2 + 1], 0, 0, 0);
            }
        }
    }

    // ---- epilogue: + b2 + residual2, LN2, store. Wave q owns channels (2q..2q+1)*16.
    float b2l[2];
#pragma unroll
    for (int cl = 0; cl < 2; ++cl) b2l[cl] = b2[(2 * q + cl) * 16 + lm];
#pragma unroll
    for (int m = 0; m < 4; ++m) {
#pragma unroll
        for (int j = 0; j < 4; ++j) {
            int row = m * 16 + lk * 4 + j;
            float s = 0.f, ss = 0.f;
#pragma unroll
            for (int cl = 0; cl < 2; ++cl) {
                int c = (2 * q + cl) * 16 + lm;
                float res = bf2f(*reinterpret_cast<const unsigned short*>(
                    xtb + row * 512 + ((c * 2) ^ ((row & 7) << 4))));
                float v = oacc[m * 2 + cl][j] + b2l[cl] + res;
                oacc[m * 2 + cl][j] = v;
                s += v;
                ss += v * v;
            }
#pragma unroll
            for (int d = 1; d < 16; d <<= 1) {
                s += __shfl_xor(s, d, 64);
                ss += __shfl_xor(ss, d, 64);
            }
            if (lm == 0) { psum[q][row] = s; psq[q][row] = ss; }
        }
    }
    __syncthreads();
    if (tid < 64) {
        float a = 0.f, b = 0.f;
#pragma unroll
        for (int qq = 0; qq < 8; ++qq) { a += psum[qq][tid]; b += psq[qq][tid]; }
        float mu2 = a * (1.f / 256.f);
        float var = b * (1.f / 256.f) - mu2 * mu2;
        stat[0][tid] = mu2;
        stat[1][tid] = rsqrtf(var + LN_EPS);
    }
    __syncthreads();
    float g2[2], be2[2];
#pragma unroll
    for (int cl = 0; cl < 2; ++cl) {
        int c = (2 * q + cl) * 16 + lm;
        g2[cl] = ln2g[c];
        be2[cl] = ln2b[c];
    }
    float* obase = out + ((size_t)(n * 6400 + p0)) * 256;
#pragma unroll
    for (int m = 0; m < 4; ++m) {
#pragma unroll
        for (int j = 0; j < 4; ++j) {
            int row = m * 16 + lk * 4 + j;
            float mu2 = stat[0][row], r2 = stat[1][row];
#pragma unroll
            for (int cl = 0; cl < 2; ++cl) {
                int c = (2 * q + cl) * 16 + lm;
                obase[(size_t)row * 256 + c] =
                    (oacc[m * 2 + cl][j] - mu2) * r2 * g2[cl] + be2[cl];
            }
        }
    }
}

extern "C" void kernel_launch(void* const* d_in, const int* in_sizes, int n_in,
                              void* d_out, int out_size, void* d_ws, size_t ws_size,
                              hipStream_t stream) {
    const float* weight = (const float*)d_in[0];   // [8,400,400]
    const float* feature = (const float*)d_in[1];  // [8,256,80,80]
    const float* ln1g = (const float*)d_in[2];
    const float* ln1b = (const float*)d_in[3];
    const float* W1 = (const float*)d_in[4];       // [1024,256]
    const float* b1 = (const float*)d_in[5];
    const float* W2 = (const float*)d_in[6];       // [256,1024]
    const float* b2 = (const float*)d_in[7];
    const float* ln2g = (const float*)d_in[8];
    const float* ln2b = (const float*)d_in[9];
    float* outp = (float*)d_out;

    float* fs = (float*)d_ws;                         // 819200 f32
    float* rbuf = fs + 819200;                        // 819200 f32
    bf8_t* W1f = (bf8_t*)(rbuf + 819200);             // 32768 frags (512 KB)
    bf8_t* W2f = W1f + 32768;                         // 32768 frags (512 KB)

    cvt_kernel<<<256, 256, 0, stream>>>(W1, W2, W1f, W2f);
    pool_kernel<<<3200, 256, 0, stream>>>(feature, fs);
    att_kernel<<<200, 256, 0, stream>>>(weight, fs, rbuf);
    main_kernel<<<800, 512, 0, stream>>>(feature, rbuf, ln1g, ln1b, W1f, b1,
                                         W2f, b2, ln2g, ln2b, outp);
}

// Round 4
// 251.005 us; speedup vs baseline: 1.1665x; 1.1665x over previous
//
#include <hip/hip_runtime.h>
#include <hip/hip_bf16.h>
#include <math.h>

#define LN_EPS 1e-5f

typedef __attribute__((ext_vector_type(4))) float f4_t;
typedef __attribute__((ext_vector_type(8))) short bf8_t;

__device__ __forceinline__ unsigned short f2bf(float x) {
    unsigned u = __builtin_bit_cast(unsigned, x);
    unsigned r = (u + 0x7FFFu + ((u >> 16) & 1u)) >> 16;
    return (unsigned short)r;
}
__device__ __forceinline__ float bf2f(unsigned short u) {
    return __builtin_bit_cast(float, ((unsigned)u) << 16);
}

// ---------------- kernel 1: reorder W1/W2 into MFMA-fragment-major bf16 -------
// W1f frag (ftile 0..63, kb 0..7): lane l holds W1[ftile*16+(l&15)][kb*32+(l>>4)*8 ..+8]
// W2f frag (ctile 0..15, kt 0..31): lane l holds W2[ctile*16+(l&15)][kt*32+(l>>4)*8 ..+8]
__global__ void cvt_kernel(const float* __restrict__ W1, const float* __restrict__ W2,
                           bf8_t* __restrict__ W1f, bf8_t* __restrict__ W2f) {
    int gid = blockIdx.x * 256 + threadIdx.x;   // 0..65535
    union { bf8_t v; unsigned short u[8]; } pk;
    if (gid < 32768) {
        int lane = gid & 63;
        int f = (gid >> 9) * 16 + (lane & 15);
        int k = ((gid >> 6) & 7) * 32 + (lane >> 4) * 8;
        const float* src = W1 + (size_t)f * 256 + k;
#pragma unroll
        for (int e = 0; e < 8; ++e) pk.u[e] = f2bf(src[e]);
        W1f[gid] = pk.v;
    } else {
        int g = gid - 32768;
        int lane = g & 63;
        int c = (g >> 11) * 16 + (lane & 15);
        int k = ((g >> 6) & 31) * 32 + (lane >> 4) * 8;
        const float* src = W2 + (size_t)c * 1024 + k;
#pragma unroll
        for (int e = 0; e < 8; ++e) pk.u[e] = f2bf(src[e]);
        W2f[g] = pk.v;
    }
}

// ---------------- kernel 2: 4x4 block pool via LDS-staged channel --------------
// block = (n, c): coalesced float4 read of the 80x80 channel into LDS, then
// 400 block-sums. fs[n][k][c].
__global__ __launch_bounds__(256) void pool_kernel(const float* __restrict__ feature,
                                                   float* __restrict__ fs) {
    __shared__ float ftile[6400];
    int b = blockIdx.x;            // n*256 + c
    int n = b >> 8, c = b & 255;
    int tid = threadIdx.x;
    const float4* src = reinterpret_cast<const float4*>(feature + ((size_t)b) * 6400);
#pragma unroll
    for (int i = 0; i < 6; ++i) {
        int idx = i * 256 + tid;                 // 0..1535
        float4 v = src[idx];
        *reinterpret_cast<float4*>(&ftile[idx * 4]) = v;
    }
    if (tid < 64) {
        int idx = 1536 + tid;
        float4 v = src[idx];
        *reinterpret_cast<float4*>(&ftile[idx * 4]) = v;
    }
    __syncthreads();
    float* dst = fs + (size_t)n * 400 * 256 + c;
#pragma unroll
    for (int pass = 0; pass < 2; ++pass) {
        int k = pass * 256 + tid;
        if (k < 400) {
            int h = k / 20, w = k % 20;
            const float* p = &ftile[(h * 4) * 80 + w * 4];
            float s = 0.f;
#pragma unroll
            for (int dh = 0; dh < 4; ++dh)
                s += p[dh * 80 + 0] + p[dh * 80 + 1] + p[dh * 80 + 2] + p[dh * 80 + 3];
            dst[(size_t)k * 256] = s;
        }
    }
}

// ---------------- kernel 3: r[n][i][c] = sum_k weight[n][i][k] * fs[n][k][c] ---
// 8 output rows per block, 400 blocks (proven R2 config).
__global__ void att_kernel(const float* __restrict__ wgt, const float* __restrict__ fs,
                           float* __restrict__ r) {
    __shared__ float fsl[16][256];
    __shared__ float wl[8][16];
    int b = blockIdx.x;
    int n = b / 50, i0 = (b % 50) * 8;
    int tid = threadIdx.x;
    const float* wbase = wgt + (size_t)n * 400 * 400;
    const float* fsbase = fs + (size_t)n * 400 * 256;
    float acc[8] = {0.f, 0.f, 0.f, 0.f, 0.f, 0.f, 0.f, 0.f};
    for (int k0 = 0; k0 < 400; k0 += 16) {
#pragma unroll
        for (int jj = 0; jj < 16; ++jj)
            fsl[jj][tid] = fsbase[(size_t)(k0 + jj) * 256 + tid];
        if (tid < 128)
            wl[tid >> 4][tid & 15] = wbase[(size_t)(i0 + (tid >> 4)) * 400 + k0 + (tid & 15)];
        __syncthreads();
#pragma unroll
        for (int kk = 0; kk < 16; ++kk) {
            float f = fsl[kk][tid];
#pragma unroll
            for (int ii = 0; ii < 8; ++ii) acc[ii] += wl[ii][kk] * f;
        }
        __syncthreads();
    }
#pragma unroll
    for (int ii = 0; ii < 8; ++ii)
        r[((size_t)n * 400 + i0 + ii) * 256 + tid] = acc[ii];
}

// ---------------- kernel 4: fused residual+att + LN1 + MLP(GELU) + LN2 ---------
// 64 tokens/block, 512 threads = 8 waves. Wave q: GEMM1 f-tile fc*8+q,
// GEMM2 c-tiles {2q,2q+1}. B-fragments batched; W2 frags issued before GELU
// so their latency hides under erff VALU work.
__global__ __launch_bounds__(512, 2) void main_kernel(
    const float* __restrict__ feat, const float* __restrict__ r,
    const float* __restrict__ ln1g, const float* __restrict__ ln1b,
    const bf8_t* __restrict__ W1f, const float* __restrict__ b1,
    const bf8_t* __restrict__ W2f, const float* __restrict__ b2,
    const float* __restrict__ ln2g, const float* __restrict__ ln2b,
    float* __restrict__ out) {
    __shared__ unsigned short xt[64 * 256];   // [t][c] swizzled, 32 KB
    __shared__ unsigned short ht[64 * 128];   // [t][f] swizzled, 16 KB
    __shared__ float psum[8][64], psq[8][64];
    __shared__ float stat[2][64];

    int bid = blockIdx.x;
    int n = bid / 100;
    int p0 = (bid % 100) * 64;
    int tid = threadIdx.x;
    int lane = tid & 63;
    int q = tid >> 6;                     // wave id 0..7
    int t = lane;                         // token row this thread loads in phase 1
    int p = p0 + t;
    int iatt = ((p / 80) >> 2) * 20 + ((p % 80) >> 2);

    // ---- phase 1: x = residual + att, LN1. Thread covers 32 channels of token t.
    const float* fbase = feat + ((size_t)(n * 256 + q * 32)) * 6400 + p;
    const float* rrow = r + ((size_t)(n * 400 + iatt)) * 256 + q * 32;
    float xv[32];
    float s1 = 0.f, s2 = 0.f;
#pragma unroll
    for (int j = 0; j < 32; ++j) {
        float v = fbase[(size_t)j * 6400] + rrow[j];
        xv[j] = v;
        s1 += v;
        s2 += v * v;
    }
    psum[q][t] = s1;
    psq[q][t] = s2;
    __syncthreads();
    if (tid < 64) {
        float a = 0.f, b = 0.f;
#pragma unroll
        for (int qq = 0; qq < 8; ++qq) { a += psum[qq][tid]; b += psq[qq][tid]; }
        float mu = a * (1.f / 256.f);
        float var = b * (1.f / 256.f) - mu * mu;
        stat[0][tid] = mu;
        stat[1][tid] = rsqrtf(var + LN_EPS);
    }
    __syncthreads();
    float mu = stat[0][t], rs = stat[1][t];
#pragma unroll
    for (int jj = 0; jj < 4; ++jj) {
        union { bf8_t v; unsigned short u[8]; } pk;
#pragma unroll
        for (int e = 0; e < 8; ++e) {
            int c = q * 32 + jj * 8 + e;
            float y = (xv[jj * 8 + e] - mu) * rs * ln1g[c] + ln1b[c];
            pk.u[e] = f2bf(y);
        }
        int byte = t * 512 + ((q * 64 + jj * 16) ^ ((t & 7) << 4));
        *reinterpret_cast<bf8_t*>(reinterpret_cast<char*>(xt) + byte) = pk.v;
    }
    __syncthreads();

    // ---- MFMA phase ----
    int lm = lane & 15, lk = lane >> 4;
    const char* xtb = reinterpret_cast<const char*>(xt);
    const char* htb = reinterpret_cast<const char*>(ht);
    char* htw = reinterpret_cast<char*>(ht);

    f4_t oacc[8];   // [m][ctl] : 4 m-tiles x 2 c-tiles
#pragma unroll
    for (int i = 0; i < 8; ++i) oacc[i] = (f4_t){0.f, 0.f, 0.f, 0.f};

    for (int fc = 0; fc < 8; ++fc) {
        // GEMM1: wave q owns f-tile fc*8+q. Batch all 8 B-frags first.
        const bf8_t* w1p = W1f + (size_t)(fc * 8 + q) * 8 * 64 + lane;
        bf8_t bfr[8];
#pragma unroll
        for (int kb = 0; kb < 8; ++kb) bfr[kb] = w1p[kb * 64];
        f4_t hacc[4];
#pragma unroll
        for (int i = 0; i < 4; ++i) hacc[i] = (f4_t){0.f, 0.f, 0.f, 0.f};
#pragma unroll
        for (int kb = 0; kb < 8; ++kb) {
#pragma unroll
            for (int m = 0; m < 4; ++m) {
                int row = m * 16 + lm;
                bf8_t a = *reinterpret_cast<const bf8_t*>(
                    xtb + row * 512 + ((kb * 64 + lk * 16) ^ ((row & 7) << 4)));
                hacc[m] = __builtin_amdgcn_mfma_f32_16x16x32_bf16(a, bfr[kb], hacc[m], 0, 0, 0);
            }
        }
        __syncthreads();   // previous fc's GEMM2 reads of ht are done
        // Issue GEMM2 B-frags now; latency hides under GELU below.
        bf8_t b2r[8];
#pragma unroll
        for (int kb = 0; kb < 4; ++kb) {
#pragma unroll
            for (int ctl = 0; ctl < 2; ++ctl)
                b2r[kb * 2 + ctl] =
                    W2f[(size_t)((2 * q + ctl) * 32 + fc * 4 + kb) * 64 + lane];
        }
        // bias + exact GELU -> swizzled ht (wave q writes cols q*16..q*16+15)
        {
            int fl = q * 16 + lm;
            float bias = b1[fc * 128 + fl];
#pragma unroll
            for (int m = 0; m < 4; ++m) {
#pragma unroll
                for (int j = 0; j < 4; ++j) {
                    int row = m * 16 + lk * 4 + j;
                    float hv = hacc[m][j] + bias;
                    float g = 0.5f * hv * (1.f + erff(hv * 0.70710678f));
                    *reinterpret_cast<unsigned short*>(
                        htw + row * 256 + ((fl * 2) ^ ((row & 7) << 4))) = f2bf(g);
                }
            }
        }
        __syncthreads();
        // GEMM2: wave q owns c-tiles {2q, 2q+1}; k-tiles fc*4..fc*4+3.
#pragma unroll
        for (int kb = 0; kb < 4; ++kb) {
#pragma unroll
            for (int m = 0; m < 4; ++m) {
                int row = m * 16 + lm;
                bf8_t a = *reinterpret_cast<const bf8_t*>(
                    htb + row * 256 + ((kb * 64 + lk * 16) ^ ((row & 7) << 4)));
                oacc[m * 2 + 0] = __builtin_amdgcn_mfma_f32_16x16x32_bf16(a, b2r[kb * 2 + 0], oacc[m * 2 + 0], 0, 0, 0);
                oacc[m * 2 + 1] = __builtin_amdgcn_mfma_f32_16x16x32_bf16(a, b2r[kb * 2 + 1], oacc[m * 2 + 1], 0, 0, 0);
            }
        }
    }

    // ---- epilogue: + b2 + residual2, LN2, store. Wave q owns channels (2q..2q+1)*16.
    float b2l[2];
#pragma unroll
    for (int cl = 0; cl < 2; ++cl) b2l[cl] = b2[(2 * q + cl) * 16 + lm];
#pragma unroll
    for (int m = 0; m < 4; ++m) {
#pragma unroll
        for (int j = 0; j < 4; ++j) {
            int row = m * 16 + lk * 4 + j;
            float s = 0.f, ss = 0.f;
#pragma unroll
            for (int cl = 0; cl < 2; ++cl) {
                int c = (2 * q + cl) * 16 + lm;
                float res = bf2f(*reinterpret_cast<const unsigned short*>(
                    xtb + row * 512 + ((c * 2) ^ ((row & 7) << 4))));
                float v = oacc[m * 2 + cl][j] + b2l[cl] + res;
                oacc[m * 2 + cl][j] = v;
                s += v;
                ss += v * v;
            }
#pragma unroll
            for (int d = 1; d < 16; d <<= 1) {
                s += __shfl_xor(s, d, 64);
                ss += __shfl_xor(ss, d, 64);
            }
            if (lm == 0) { psum[q][row] = s; psq[q][row] = ss; }
        }
    }
    __syncthreads();
    if (tid < 64) {
        float a = 0.f, b = 0.f;
#pragma unroll
        for (int qq = 0; qq < 8; ++qq) { a += psum[qq][tid]; b += psq[qq][tid]; }
        float mu2 = a * (1.f / 256.f);
        float var = b * (1.f / 256.f) - mu2 * mu2;
        stat[0][tid] = mu2;
        stat[1][tid] = rsqrtf(var + LN_EPS);
    }
    __syncthreads();
    float g2[2], be2[2];
#pragma unroll
    for (int cl = 0; cl < 2; ++cl) {
        int c = (2 * q + cl) * 16 + lm;
        g2[cl] = ln2g[c];
        be2[cl] = ln2b[c];
    }
    float* obase = out + ((size_t)(n * 6400 + p0)) * 256;
#pragma unroll
    for (int m = 0; m < 4; ++m) {
#pragma unroll
        for (int j = 0; j < 4; ++j) {
            int row = m * 16 + lk * 4 + j;
            float mu2 = stat[0][row], r2 = stat[1][row];
#pragma unroll
            for (int cl = 0; cl < 2; ++cl) {
                int c = (2 * q + cl) * 16 + lm;
                obase[(size_t)row * 256 + c] =
                    (oacc[m * 2 + cl][j] - mu2) * r2 * g2[cl] + be2[cl];
            }
        }
    }
}

extern "C" void kernel_launch(void* const* d_in, const int* in_sizes, int n_in,
                              void* d_out, int out_size, void* d_ws, size_t ws_size,
                              hipStream_t stream) {
    const float* weight = (const float*)d_in[0];   // [8,400,400]
    const float* feature = (const float*)d_in[1];  // [8,256,80,80]
    const float* ln1g = (const float*)d_in[2];
    const float* ln1b = (const float*)d_in[3];
    const float* W1 = (const float*)d_in[4];       // [1024,256]
    const float* b1 = (const float*)d_in[5];
    const float* W2 = (const float*)d_in[6];       // [256,1024]
    const float* b2 = (const float*)d_in[7];
    const float* ln2g = (const float*)d_in[8];
    const float* ln2b = (const float*)d_in[9];
    float* outp = (float*)d_out;

    float* fs = (float*)d_ws;                         // 819200 f32
    float* rbuf = fs + 819200;                        // 819200 f32
    bf8_t* W1f = (bf8_t*)(rbuf + 819200);             // 32768 frags (512 KB)
    bf8_t* W2f = W1f + 32768;                         // 32768 frags (512 KB)

    cvt_kernel<<<256, 256, 0, stream>>>(W1, W2, W1f, W2f);
    pool_kernel<<<2048, 256, 0, stream>>>(feature, fs);
    att_kernel<<<400, 256, 0, stream>>>(weight, fs, rbuf);
    main_kernel<<<800, 512, 0, stream>>>(feature, rbuf, ln1g, ln1b, W1f, b1,
                                         W2f, b2, ln2g, ln2b, outp);
}

// Round 6
// 195.322 us; speedup vs baseline: 1.4990x; 1.2851x over previous
//
#include <hip/hip_runtime.h>
#include <hip/hip_bf16.h>
#include <math.h>

#define LN_EPS 1e-5f

typedef __attribute__((ext_vector_type(4))) float f4_t;
typedef __attribute__((ext_vector_type(8))) short bf8_t;

__device__ __forceinline__ unsigned short f2bf(float x) {
    unsigned u = __builtin_bit_cast(unsigned, x);
    unsigned r = (u + 0x7FFFu + ((u >> 16) & 1u)) >> 16;
    return (unsigned short)r;
}
__device__ __forceinline__ float bf2f(unsigned short u) {
    return __builtin_bit_cast(float, ((unsigned)u) << 16);
}
// exact GELU: 0.5x(1+erf(x/sqrt2)), erf via A&S 7.1.26 (|eps|<=1.5e-7)
__device__ __forceinline__ float gelu_f(float x) {
    float z = x * 0.70710678f;
    float az = fabsf(z);
    float t = __builtin_amdgcn_rcpf(1.f + 0.3275911f * az);
    float y = t * (0.254829592f + t * (-0.284496736f + t * (1.421413741f +
              t * (-1.453152027f + t * 1.061405429f))));
    float e = 1.f - y * __expf(-az * az);
    return 0.5f * x * (1.f + copysignf(e, x));
}

// ---------------- kernel 1: reorder W1/W2 into MFMA-fragment-major bf16 -------
// W1f frag (ftile 0..63, kb 0..7): lane l holds W1[ftile*16+(l&15)][kb*32+(l>>4)*8 ..+8]
// W2f frag (ctile 0..15, kt 0..31): lane l holds W2[ctile*16+(l&15)][kt*32+(l>>4)*8 ..+8]
__global__ void cvt_kernel(const float* __restrict__ W1, const float* __restrict__ W2,
                           bf8_t* __restrict__ W1f, bf8_t* __restrict__ W2f) {
    int gid = blockIdx.x * 256 + threadIdx.x;   // 0..65535
    union { bf8_t v; unsigned short u[8]; } pk;
    if (gid < 32768) {
        int lane = gid & 63;
        int f = (gid >> 9) * 16 + (lane & 15);
        int k = ((gid >> 6) & 7) * 32 + (lane >> 4) * 8;
        const float* src = W1 + (size_t)f * 256 + k;
#pragma unroll
        for (int e = 0; e < 8; ++e) pk.u[e] = f2bf(src[e]);
        W1f[gid] = pk.v;
    } else {
        int g = gid - 32768;
        int lane = g & 63;
        int c = (g >> 11) * 16 + (lane & 15);
        int k = ((g >> 6) & 31) * 32 + (lane >> 4) * 8;
        const float* src = W2 + (size_t)c * 1024 + k;
#pragma unroll
        for (int e = 0; e < 8; ++e) pk.u[e] = f2bf(src[e]);
        W2f[g] = pk.v;
    }
}

// ---------------- kernel 2: 4x4 block pool via LDS-staged channel --------------
__global__ __launch_bounds__(256) void pool_kernel(const float* __restrict__ feature,
                                                   float* __restrict__ fs) {
    __shared__ float ftile[6400];
    int b = blockIdx.x;            // n*256 + c
    int n = b >> 8, c = b & 255;
    int tid = threadIdx.x;
    const float4* src = reinterpret_cast<const float4*>(feature + ((size_t)b) * 6400);
#pragma unroll
    for (int i = 0; i < 6; ++i) {
        int idx = i * 256 + tid;                 // 0..1535
        float4 v = src[idx];
        *reinterpret_cast<float4*>(&ftile[idx * 4]) = v;
    }
    if (tid < 64) {
        int idx = 1536 + tid;
        float4 v = src[idx];
        *reinterpret_cast<float4*>(&ftile[idx * 4]) = v;
    }
    __syncthreads();
    float* dst = fs + (size_t)n * 400 * 256 + c;
#pragma unroll
    for (int pass = 0; pass < 2; ++pass) {
        int k = pass * 256 + tid;
        if (k < 400) {
            int h = k / 20, w = k % 20;
            const float* p = &ftile[(h * 4) * 80 + w * 4];
            float s = 0.f;
#pragma unroll
            for (int dh = 0; dh < 4; ++dh)
                s += p[dh * 80 + 0] + p[dh * 80 + 1] + p[dh * 80 + 2] + p[dh * 80 + 3];
            dst[(size_t)k * 256] = s;
        }
    }
}

// ---------------- kernel 3: r[n][i][c] = sum_k weight[n][i][k] * fs[n][k][c] ---
__global__ void att_kernel(const float* __restrict__ wgt, const float* __restrict__ fs,
                           float* __restrict__ r) {
    __shared__ float fsl[16][256];
    __shared__ float wl[8][16];
    int b = blockIdx.x;
    int n = b / 50, i0 = (b % 50) * 8;
    int tid = threadIdx.x;
    const float* wbase = wgt + (size_t)n * 400 * 400;
    const float* fsbase = fs + (size_t)n * 400 * 256;
    float acc[8] = {0.f, 0.f, 0.f, 0.f, 0.f, 0.f, 0.f, 0.f};
    for (int k0 = 0; k0 < 400; k0 += 16) {
#pragma unroll
        for (int jj = 0; jj < 16; ++jj)
            fsl[jj][tid] = fsbase[(size_t)(k0 + jj) * 256 + tid];
        if (tid < 128)
            wl[tid >> 4][tid & 15] = wbase[(size_t)(i0 + (tid >> 4)) * 400 + k0 + (tid & 15)];
        __syncthreads();
#pragma unroll
        for (int kk = 0; kk < 16; ++kk) {
            float f = fsl[kk][tid];
#pragma unroll
            for (int ii = 0; ii < 8; ++ii) acc[ii] += wl[ii][kk] * f;
        }
        __syncthreads();
    }
#pragma unroll
    for (int ii = 0; ii < 8; ++ii)
        r[((size_t)n * 400 + i0 + ii) * 256 + tid] = acc[ii];
}

// ---------------- kernel 4: fused residual+att + LN1 + MLP(GELU) + LN2 ---------
// 32 tokens/block, 256 threads = 4 waves, 1600 blocks (~6 blocks/CU by LDS).
// Wave q: GEMM1 f-tiles {2q,2q+1} of each 128-f chunk; GEMM2 c-tiles 4q..4q+3.
__global__ __launch_bounds__(256, 4) void main_kernel(
    const float* __restrict__ feat, const float* __restrict__ r,
    const float* __restrict__ ln1g, const float* __restrict__ ln1b,
    const bf8_t* __restrict__ W1f, const float* __restrict__ b1,
    const bf8_t* __restrict__ W2f, const float* __restrict__ b2,
    const float* __restrict__ ln2g, const float* __restrict__ ln2b,
    float* __restrict__ out) {
    __shared__ unsigned short xt[32 * 256];   // [t][c] swizzled, 16 KB
    __shared__ unsigned short ht[32 * 128];   // [t][f] swizzled, 8 KB
    __shared__ float psum[8][32], psq[8][32];
    __shared__ float stat[2][32];

    int bid = blockIdx.x;
    int n = bid / 200;
    int p0 = (bid % 200) * 32;
    int tid = threadIdx.x;
    int lane = tid & 63;
    int q = tid >> 6;                     // wave id 0..3
    int t = tid & 31;                     // token row (phase 1)
    int g = tid >> 5;                     // channel group 0..7 (phase 1)
    int p = p0 + t;
    int iatt = ((p / 80) >> 2) * 20 + ((p % 80) >> 2);

    // ---- phase 1: x = residual + att, LN1. Thread covers 32 channels of token t.
    const float* fbase = feat + ((size_t)(n * 256 + g * 32)) * 6400 + p;
    const float* rrow = r + ((size_t)(n * 400 + iatt)) * 256 + g * 32;
    float xv[32];
    float s1 = 0.f, s2 = 0.f;
#pragma unroll
    for (int j = 0; j < 32; ++j) {
        float v = fbase[(size_t)j * 6400] + rrow[j];
        xv[j] = v;
        s1 += v;
        s2 += v * v;
    }
    psum[g][t] = s1;
    psq[g][t] = s2;
    __syncthreads();
    if (tid < 32) {
        float a = 0.f, b = 0.f;
#pragma unroll
        for (int gg = 0; gg < 8; ++gg) { a += psum[gg][tid]; b += psq[gg][tid]; }
        float mu = a * (1.f / 256.f);
        float var = b * (1.f / 256.f) - mu * mu;
        stat[0][tid] = mu;
        stat[1][tid] = rsqrtf(var + LN_EPS);
    }
    __syncthreads();
    float mu = stat[0][t], rs = stat[1][t];
#pragma unroll
    for (int jj = 0; jj < 4; ++jj) {
        union { bf8_t v; unsigned short u[8]; } pk;
#pragma unroll
        for (int e = 0; e < 8; ++e) {
            int c = g * 32 + jj * 8 + e;
            float y = (xv[jj * 8 + e] - mu) * rs * ln1g[c] + ln1b[c];
            pk.u[e] = f2bf(y);
        }
        int byte = t * 512 + ((g * 64 + jj * 16) ^ ((t & 7) << 4));
        *reinterpret_cast<bf8_t*>(reinterpret_cast<char*>(xt) + byte) = pk.v;
    }
    __syncthreads();

    // ---- MFMA phase ----
    int lm = lane & 15, lk = lane >> 4;
    const char* xtb = reinterpret_cast<const char*>(xt);
    const char* htb = reinterpret_cast<const char*>(ht);
    char* htw = reinterpret_cast<char*>(ht);

    f4_t oacc[8];   // [m*4+cl] : 2 m-tiles x 4 c-tiles
#pragma unroll
    for (int i = 0; i < 8; ++i) oacc[i] = (f4_t){0.f, 0.f, 0.f, 0.f};

    for (int fc = 0; fc < 8; ++fc) {
        // GEMM1: wave q owns f-tiles {2q, 2q+1} of this 128-f chunk.
        const bf8_t* w1p = W1f + ((size_t)(fc * 8 + 2 * q) * 8) * 64 + lane;
        f4_t hacc[4];   // [m*2+ftl]
#pragma unroll
        for (int i = 0; i < 4; ++i) hacc[i] = (f4_t){0.f, 0.f, 0.f, 0.f};
#pragma unroll
        for (int half = 0; half < 2; ++half) {
            bf8_t bfr[8];
#pragma unroll
            for (int kb = 0; kb < 4; ++kb) {
                bfr[kb * 2 + 0] = w1p[(0 * 8 + half * 4 + kb) * 64];
                bfr[kb * 2 + 1] = w1p[(1 * 8 + half * 4 + kb) * 64];
            }
#pragma unroll
            for (int kb = 0; kb < 4; ++kb) {
                int kbb = half * 4 + kb;
#pragma unroll
                for (int m = 0; m < 2; ++m) {
                    int row = m * 16 + lm;
                    bf8_t a = *reinterpret_cast<const bf8_t*>(
                        xtb + row * 512 + ((kbb * 64 + lk * 16) ^ ((row & 7) << 4)));
                    hacc[m * 2 + 0] = __builtin_amdgcn_mfma_f32_16x16x32_bf16(a, bfr[kb * 2 + 0], hacc[m * 2 + 0], 0, 0, 0);
                    hacc[m * 2 + 1] = __builtin_amdgcn_mfma_f32_16x16x32_bf16(a, bfr[kb * 2 + 1], hacc[m * 2 + 1], 0, 0, 0);
                }
            }
        }
        __syncthreads();   // previous fc's GEMM2 reads of ht are done
        // issue first half of GEMM2 B-frags; latency hides under GELU
        const bf8_t* w2p = W2f + ((size_t)(q * 4) * 32 + fc * 4) * 64 + lane;
        bf8_t b2rA[8];
#pragma unroll
        for (int kb = 0; kb < 4; ++kb) {
            b2rA[kb * 2 + 0] = w2p[(0 * 32 + kb) * 64];
            b2rA[kb * 2 + 1] = w2p[(1 * 32 + kb) * 64];
        }
        // bias + exact GELU -> swizzled ht (wave q owns cols (2q..2q+1)*16)
#pragma unroll
        for (int ftl = 0; ftl < 2; ++ftl) {
            int fl = (2 * q + ftl) * 16 + lm;
            float bias = b1[fc * 128 + fl];
#pragma unroll
            for (int m = 0; m < 2; ++m) {
#pragma unroll
                for (int j = 0; j < 4; ++j) {
                    int row = m * 16 + lk * 4 + j;
                    float gv = gelu_f(hacc[m * 2 + ftl][j] + bias);
                    *reinterpret_cast<unsigned short*>(
                        htw + row * 256 + ((fl * 2) ^ ((row & 7) << 4))) = f2bf(gv);
                }
            }
        }
        __syncthreads();
        // second half of B-frags in flight during first MFMA batch
        bf8_t b2rB[8];
#pragma unroll
        for (int kb = 0; kb < 4; ++kb) {
            b2rB[kb * 2 + 0] = w2p[(2 * 32 + kb) * 64];
            b2rB[kb * 2 + 1] = w2p[(3 * 32 + kb) * 64];
        }
        bf8_t ah[2][4];
#pragma unroll
        for (int kb = 0; kb < 4; ++kb) {
#pragma unroll
            for (int m = 0; m < 2; ++m) {
                int row = m * 16 + lm;
                ah[m][kb] = *reinterpret_cast<const bf8_t*>(
                    htb + row * 256 + ((kb * 64 + lk * 16) ^ ((row & 7) << 4)));
                oacc[m * 4 + 0] = __builtin_amdgcn_mfma_f32_16x16x32_bf16(ah[m][kb], b2rA[kb * 2 + 0], oacc[m * 4 + 0], 0, 0, 0);
                oacc[m * 4 + 1] = __builtin_amdgcn_mfma_f32_16x16x32_bf16(ah[m][kb], b2rA[kb * 2 + 1], oacc[m * 4 + 1], 0, 0, 0);
            }
        }
#pragma unroll
        for (int kb = 0; kb < 4; ++kb) {
#pragma unroll
            for (int m = 0; m < 2; ++m) {
                oacc[m * 4 + 2] = __builtin_amdgcn_mfma_f32_16x16x32_bf16(ah[m][kb], b2rB[kb * 2 + 0], oacc[m * 4 + 2], 0, 0, 0);
                oacc[m * 4 + 3] = __builtin_amdgcn_mfma_f32_16x16x32_bf16(ah[m][kb], b2rB[kb * 2 + 1], oacc[m * 4 + 3], 0, 0, 0);
            }
        }
    }

    // ---- epilogue: + b2 + residual2, LN2, store. Wave q owns channels (4q..4q+3)*16.
    float b2l[4];
#pragma unroll
    for (int cl = 0; cl < 4; ++cl) b2l[cl] = b2[(q * 4 + cl) * 16 + lm];
#pragma unroll
    for (int m = 0; m < 2; ++m) {
#pragma unroll
        for (int j = 0; j < 4; ++j) {
            int row = m * 16 + lk * 4 + j;
            float s = 0.f, ss = 0.f;
#pragma unroll
            for (int cl = 0; cl < 4; ++cl) {
                int c = (q * 4 + cl) * 16 + lm;
                float res = bf2f(*reinterpret_cast<const unsigned short*>(
                    xtb + row * 512 + ((c * 2) ^ ((row & 7) << 4))));
                float v = oacc[m * 4 + cl][j] + b2l[cl] + res;
                oacc[m * 4 + cl][j] = v;
                s += v;
                ss += v * v;
            }
#pragma unroll
            for (int d = 1; d < 16; d <<= 1) {
                s += __shfl_xor(s, d, 64);
                ss += __shfl_xor(ss, d, 64);
            }
            if (lm == 0) { psum[q][row] = s; psq[q][row] = ss; }
        }
    }
    __syncthreads();
    if (tid < 32) {
        float a = 0.f, b = 0.f;
#pragma unroll
        for (int qq = 0; qq < 4; ++qq) { a += psum[qq][tid]; b += psq[qq][tid]; }
        float mu2 = a * (1.f / 256.f);
        float var = b * (1.f / 256.f) - mu2 * mu2;
        stat[0][tid] = mu2;
        stat[1][tid] = rsqrtf(var + LN_EPS);
    }
    __syncthreads();
    float g2[4], be2[4];
#pragma unroll
    for (int cl = 0; cl < 4; ++cl) {
        int c = (q * 4 + cl) * 16 + lm;
        g2[cl] = ln2g[c];
        be2[cl] = ln2b[c];
    }
    float* obase = out + ((size_t)(n * 6400 + p0)) * 256;
#pragma unroll
    for (int m = 0; m < 2; ++m) {
#pragma unroll
        for (int j = 0; j < 4; ++j) {
            int row = m * 16 + lk * 4 + j;
            float mu2 = stat[0][row], r2 = stat[1][row];
#pragma unroll
            for (int cl = 0; cl < 4; ++cl) {
                int c = (q * 4 + cl) * 16 + lm;
                obase[(size_t)row * 256 + c] =
                    (oacc[m * 4 + cl][j] - mu2) * r2 * g2[cl] + be2[cl];
            }
        }
    }
}

extern "C" void kernel_launch(void* const* d_in, const int* in_sizes, int n_in,
                              void* d_out, int out_size, void* d_ws, size_t ws_size,
                              hipStream_t stream) {
    const float* weight = (const float*)d_in[0];   // [8,400,400]
    const float* feature = (const float*)d_in[1];  // [8,256,80,80]
    const float* ln1g = (const float*)d_in[2];
    const float* ln1b = (const float*)d_in[3];
    const float* W1 = (const float*)d_in[4];       // [1024,256]
    const float* b1 = (const float*)d_in[5];
    const float* W2 = (const float*)d_in[6];       // [256,1024]
    const float* b2 = (const float*)d_in[7];
    const float* ln2g = (const float*)d_in[8];
    const float* ln2b = (const float*)d_in[9];
    float* outp = (float*)d_out;

    float* fs = (float*)d_ws;                         // 819200 f32
    float* rbuf = fs + 819200;                        // 819200 f32
    bf8_t* W1f = (bf8_t*)(rbuf + 819200);             // 32768 frags (512 KB)
    bf8_t* W2f = W1f + 32768;                         // 32768 frags (512 KB)

    cvt_kernel<<<256, 256, 0, stream>>>(W1, W2, W1f, W2f);
    pool_kernel<<<2048, 256, 0, stream>>>(feature, fs);
    att_kernel<<<400, 256, 0, stream>>>(weight, fs, rbuf);
    main_kernel<<<1600, 256, 0, stream>>>(feature, rbuf, ln1g, ln1b, W1f, b1,
                                          W2f, b2, ln2g, ln2b, outp);
}

// Round 7
// 191.095 us; speedup vs baseline: 1.5322x; 1.0221x over previous
//
#include <hip/hip_runtime.h>
#include <hip/hip_bf16.h>
#include <math.h>

#define LN_EPS 1e-5f

typedef __attribute__((ext_vector_type(4))) float f4_t;
typedef __attribute__((ext_vector_type(8))) short bf8_t;

__device__ __forceinline__ unsigned short f2bf(float x) {
    unsigned u = __builtin_bit_cast(unsigned, x);
    unsigned r = (u + 0x7FFFu + ((u >> 16) & 1u)) >> 16;
    return (unsigned short)r;
}
__device__ __forceinline__ float bf2f(unsigned short u) {
    return __builtin_bit_cast(float, ((unsigned)u) << 16);
}
// exact GELU: 0.5x(1+erf(x/sqrt2)), erf via A&S 7.1.26 (|eps|<=1.5e-7)
__device__ __forceinline__ float gelu_f(float x) {
    float z = x * 0.70710678f;
    float az = fabsf(z);
    float t = __builtin_amdgcn_rcpf(1.f + 0.3275911f * az);
    float y = t * (0.254829592f + t * (-0.284496736f + t * (1.421413741f +
              t * (-1.453152027f + t * 1.061405429f))));
    float e = 1.f - y * __expf(-az * az);
    return 0.5f * x * (1.f + copysignf(e, x));
}

// ---------------- kernel 1: reorder W1/W2 into MFMA-fragment-major bf16 -------
// W1f frag (ftile 0..63, kb 0..7): lane l holds W1[ftile*16+(l&15)][kb*32+(l>>4)*8 ..+8]
// W2f frag (ctile 0..15, kt 0..31): lane l holds W2[ctile*16+(l&15)][kt*32+(l>>4)*8 ..+8]
__global__ void cvt_kernel(const float* __restrict__ W1, const float* __restrict__ W2,
                           bf8_t* __restrict__ W1f, bf8_t* __restrict__ W2f) {
    int gid = blockIdx.x * 256 + threadIdx.x;   // 0..65535
    union { bf8_t v; unsigned short u[8]; } pk;
    if (gid < 32768) {
        int lane = gid & 63;
        int f = (gid >> 9) * 16 + (lane & 15);
        int k = ((gid >> 6) & 7) * 32 + (lane >> 4) * 8;
        const float* src = W1 + (size_t)f * 256 + k;
#pragma unroll
        for (int e = 0; e < 8; ++e) pk.u[e] = f2bf(src[e]);
        W1f[gid] = pk.v;
    } else {
        int g = gid - 32768;
        int lane = g & 63;
        int c = (g >> 11) * 16 + (lane & 15);
        int k = ((g >> 6) & 31) * 32 + (lane >> 4) * 8;
        const float* src = W2 + (size_t)c * 1024 + k;
#pragma unroll
        for (int e = 0; e < 8; ++e) pk.u[e] = f2bf(src[e]);
        W2f[g] = pk.v;
    }
}

// ---------------- kernel 2: 4x4 block pool via LDS-staged channel --------------
__global__ __launch_bounds__(256) void pool_kernel(const float* __restrict__ feature,
                                                   float* __restrict__ fs) {
    __shared__ float ftile[6400];
    int b = blockIdx.x;            // n*256 + c
    int n = b >> 8, c = b & 255;
    int tid = threadIdx.x;
    const float4* src = reinterpret_cast<const float4*>(feature + ((size_t)b) * 6400);
#pragma unroll
    for (int i = 0; i < 6; ++i) {
        int idx = i * 256 + tid;                 // 0..1535
        float4 v = src[idx];
        *reinterpret_cast<float4*>(&ftile[idx * 4]) = v;
    }
    if (tid < 64) {
        int idx = 1536 + tid;
        float4 v = src[idx];
        *reinterpret_cast<float4*>(&ftile[idx * 4]) = v;
    }
    __syncthreads();
    float* dst = fs + (size_t)n * 400 * 256 + c;
#pragma unroll
    for (int pass = 0; pass < 2; ++pass) {
        int k = pass * 256 + tid;
        if (k < 400) {
            int h = k / 20, w = k % 20;
            const float* p = &ftile[(h * 4) * 80 + w * 4];
            float s = 0.f;
#pragma unroll
            for (int dh = 0; dh < 4; ++dh)
                s += p[dh * 80 + 0] + p[dh * 80 + 1] + p[dh * 80 + 2] + p[dh * 80 + 3];
            dst[(size_t)k * 256] = s;
        }
    }
}

// ---------------- kernel 3: r[n][i][c] = sum_k weight[n][i][k] * fs[n][k][c] ---
__global__ void att_kernel(const float* __restrict__ wgt, const float* __restrict__ fs,
                           float* __restrict__ r) {
    __shared__ float fsl[16][256];
    __shared__ float wl[8][16];
    int b = blockIdx.x;
    int n = b / 50, i0 = (b % 50) * 8;
    int tid = threadIdx.x;
    const float* wbase = wgt + (size_t)n * 400 * 400;
    const float* fsbase = fs + (size_t)n * 400 * 256;
    float acc[8] = {0.f, 0.f, 0.f, 0.f, 0.f, 0.f, 0.f, 0.f};
    for (int k0 = 0; k0 < 400; k0 += 16) {
#pragma unroll
        for (int jj = 0; jj < 16; ++jj)
            fsl[jj][tid] = fsbase[(size_t)(k0 + jj) * 256 + tid];
        if (tid < 128)
            wl[tid >> 4][tid & 15] = wbase[(size_t)(i0 + (tid >> 4)) * 400 + k0 + (tid & 15)];
        __syncthreads();
#pragma unroll
        for (int kk = 0; kk < 16; ++kk) {
            float f = fsl[kk][tid];
#pragma unroll
            for (int ii = 0; ii < 8; ++ii) acc[ii] += wl[ii][kk] * f;
        }
        __syncthreads();
    }
#pragma unroll
    for (int ii = 0; ii < 8; ++ii)
        r[((size_t)n * 400 + i0 + ii) * 256 + tid] = acc[ii];
}

// ---------------- kernel 4: fused residual+att + LN1 + MLP(GELU) + LN2 ---------
// 32 tokens/block, 256 threads = 4 waves, 1600 blocks. Pinned 4 waves/EU
// (128-VGPR cap, no spill). ht double-buffered -> 1 barrier per fc chunk.
__attribute__((amdgpu_waves_per_eu(4, 4)))
__global__ __launch_bounds__(256) void main_kernel(
    const float* __restrict__ feat, const float* __restrict__ r,
    const float* __restrict__ ln1g, const float* __restrict__ ln1b,
    const bf8_t* __restrict__ W1f, const float* __restrict__ b1,
    const bf8_t* __restrict__ W2f, const float* __restrict__ b2,
    const float* __restrict__ ln2g, const float* __restrict__ ln2b,
    float* __restrict__ out) {
    __shared__ unsigned short xt[32 * 256];      // [t][c] swizzled, 16 KB
    __shared__ unsigned short ht[2][32 * 128];   // dbuf [t][f] swizzled, 2x8 KB
    __shared__ float psum[8][32], psq[8][32];
    __shared__ float stat[2][32];

    int bid = blockIdx.x;
    int n = bid / 200;
    int p0 = (bid % 200) * 32;
    int tid = threadIdx.x;
    int lane = tid & 63;
    int q = tid >> 6;                     // wave id 0..3
    int t = tid & 31;                     // token row (phase 1)
    int g = tid >> 5;                     // channel group 0..7 (phase 1)
    int p = p0 + t;
    int iatt = ((p / 80) >> 2) * 20 + ((p % 80) >> 2);

    // ---- phase 1: x = residual + att, LN1. Thread covers 32 channels of token t.
    const float* fbase = feat + ((size_t)(n * 256 + g * 32)) * 6400 + p;
    const float* rrow = r + ((size_t)(n * 400 + iatt)) * 256 + g * 32;
    float xv[32];
    float s1 = 0.f, s2 = 0.f;
#pragma unroll
    for (int j = 0; j < 32; ++j) {
        float v = fbase[(size_t)j * 6400] + rrow[j];
        xv[j] = v;
        s1 += v;
        s2 += v * v;
    }
    psum[g][t] = s1;
    psq[g][t] = s2;
    __syncthreads();
    if (tid < 32) {
        float a = 0.f, b = 0.f;
#pragma unroll
        for (int gg = 0; gg < 8; ++gg) { a += psum[gg][tid]; b += psq[gg][tid]; }
        float mu = a * (1.f / 256.f);
        float var = b * (1.f / 256.f) - mu * mu;
        stat[0][tid] = mu;
        stat[1][tid] = rsqrtf(var + LN_EPS);
    }
    __syncthreads();
    float mu = stat[0][t], rs = stat[1][t];
#pragma unroll
    for (int jj = 0; jj < 4; ++jj) {
        union { bf8_t v; unsigned short u[8]; } pk;
#pragma unroll
        for (int e = 0; e < 8; ++e) {
            int c = g * 32 + jj * 8 + e;
            float y = (xv[jj * 8 + e] - mu) * rs * ln1g[c] + ln1b[c];
            pk.u[e] = f2bf(y);
        }
        int byte = t * 512 + ((g * 64 + jj * 16) ^ ((t & 7) << 4));
        *reinterpret_cast<bf8_t*>(reinterpret_cast<char*>(xt) + byte) = pk.v;
    }
    __syncthreads();

    // ---- MFMA phase ----
    int lm = lane & 15, lk = lane >> 4;
    const char* xtb = reinterpret_cast<const char*>(xt);

    f4_t oacc[8];   // [m*4+cl] : 2 m-tiles x 4 c-tiles
#pragma unroll
    for (int i = 0; i < 8; ++i) oacc[i] = (f4_t){0.f, 0.f, 0.f, 0.f};

    for (int fc = 0; fc < 8; ++fc) {
        char* htc = reinterpret_cast<char*>(ht[fc & 1]);
        // GEMM1: wave q owns f-tiles {2q, 2q+1} of this 128-f chunk.
        const bf8_t* w1p = W1f + ((size_t)(fc * 8 + 2 * q) * 8) * 64 + lane;
        f4_t hacc[4];   // [m*2+ftl]
#pragma unroll
        for (int i = 0; i < 4; ++i) hacc[i] = (f4_t){0.f, 0.f, 0.f, 0.f};
#pragma unroll
        for (int half = 0; half < 2; ++half) {
            bf8_t bfr[8];
#pragma unroll
            for (int kb = 0; kb < 4; ++kb) {
                bfr[kb * 2 + 0] = w1p[(0 * 8 + half * 4 + kb) * 64];
                bfr[kb * 2 + 1] = w1p[(1 * 8 + half * 4 + kb) * 64];
            }
#pragma unroll
            for (int kb = 0; kb < 4; ++kb) {
                int kbb = half * 4 + kb;
#pragma unroll
                for (int m = 0; m < 2; ++m) {
                    int row = m * 16 + lm;
                    bf8_t a = *reinterpret_cast<const bf8_t*>(
                        xtb + row * 512 + ((kbb * 64 + lk * 16) ^ ((row & 7) << 4)));
                    hacc[m * 2 + 0] = __builtin_amdgcn_mfma_f32_16x16x32_bf16(a, bfr[kb * 2 + 0], hacc[m * 2 + 0], 0, 0, 0);
                    hacc[m * 2 + 1] = __builtin_amdgcn_mfma_f32_16x16x32_bf16(a, bfr[kb * 2 + 1], hacc[m * 2 + 1], 0, 0, 0);
                }
            }
        }
        // issue GEMM2 B-frags for c-tiles {4q, 4q+1}; latency hides under GELU
        const bf8_t* w2p = W2f + ((size_t)(q * 4) * 32 + fc * 4) * 64 + lane;
        bf8_t b2rA[8];
#pragma unroll
        for (int kb = 0; kb < 4; ++kb) {
            b2rA[kb * 2 + 0] = w2p[(0 * 32 + kb) * 64];
            b2rA[kb * 2 + 1] = w2p[(1 * 32 + kb) * 64];
        }
        // bias + exact GELU -> swizzled ht[fc&1] (wave q owns cols (2q..2q+1)*16)
#pragma unroll
        for (int ftl = 0; ftl < 2; ++ftl) {
            int fl = (2 * q + ftl) * 16 + lm;
            float bias = b1[fc * 128 + fl];
#pragma unroll
            for (int m = 0; m < 2; ++m) {
#pragma unroll
                for (int j = 0; j < 4; ++j) {
                    int row = m * 16 + lk * 4 + j;
                    float gv = gelu_f(hacc[m * 2 + ftl][j] + bias);
                    *reinterpret_cast<unsigned short*>(
                        htc + row * 256 + ((fl * 2) ^ ((row & 7) << 4))) = f2bf(gv);
                }
            }
        }
        __syncthreads();   // ht[fc&1] ready (also orders prev-fc reads vs next writes)
        // issue second half of B-frags (c-tiles {4q+2, 4q+3})
        bf8_t b2rB[8];
#pragma unroll
        for (int kb = 0; kb < 4; ++kb) {
            b2rB[kb * 2 + 0] = w2p[(2 * 32 + kb) * 64];
            b2rB[kb * 2 + 1] = w2p[(3 * 32 + kb) * 64];
        }
        // GEMM2 ct pair 0 (reads a from LDS, no register batching of a)
#pragma unroll
        for (int kb = 0; kb < 4; ++kb) {
#pragma unroll
            for (int m = 0; m < 2; ++m) {
                int row = m * 16 + lm;
                bf8_t a = *reinterpret_cast<const bf8_t*>(
                    htc + row * 256 + ((kb * 64 + lk * 16) ^ ((row & 7) << 4)));
                oacc[m * 4 + 0] = __builtin_amdgcn_mfma_f32_16x16x32_bf16(a, b2rA[kb * 2 + 0], oacc[m * 4 + 0], 0, 0, 0);
                oacc[m * 4 + 1] = __builtin_amdgcn_mfma_f32_16x16x32_bf16(a, b2rA[kb * 2 + 1], oacc[m * 4 + 1], 0, 0, 0);
            }
        }
        // GEMM2 ct pair 1
#pragma unroll
        for (int kb = 0; kb < 4; ++kb) {
#pragma unroll
            for (int m = 0; m < 2; ++m) {
                int row = m * 16 + lm;
                bf8_t a = *reinterpret_cast<const bf8_t*>(
                    htc + row * 256 + ((kb * 64 + lk * 16) ^ ((row & 7) << 4)));
                oacc[m * 4 + 2] = __builtin_amdgcn_mfma_f32_16x16x32_bf16(a, b2rB[kb * 2 + 0], oacc[m * 4 + 2], 0, 0, 0);
                oacc[m * 4 + 3] = __builtin_amdgcn_mfma_f32_16x16x32_bf16(a, b2rB[kb * 2 + 1], oacc[m * 4 + 3], 0, 0, 0);
            }
        }
    }

    // ---- epilogue: + b2 + residual2, LN2, store. Wave q owns channels (4q..4q+3)*16.
    float b2l[4];
#pragma unroll
    for (int cl = 0; cl < 4; ++cl) b2l[cl] = b2[(q * 4 + cl) * 16 + lm];
#pragma unroll
    for (int m = 0; m < 2; ++m) {
#pragma unroll
        for (int j = 0; j < 4; ++j) {
            int row = m * 16 + lk * 4 + j;
            float s = 0.f, ss = 0.f;
#pragma unroll
            for (int cl = 0; cl < 4; ++cl) {
                int c = (q * 4 + cl) * 16 + lm;
                float res = bf2f(*reinterpret_cast<const unsigned short*>(
                    xtb + row * 512 + ((c * 2) ^ ((row & 7) << 4))));
                float v = oacc[m * 4 + cl][j] + b2l[cl] + res;
                oacc[m * 4 + cl][j] = v;
                s += v;
                ss += v * v;
            }
#pragma unroll
            for (int d = 1; d < 16; d <<= 1) {
                s += __shfl_xor(s, d, 64);
                ss += __shfl_xor(ss, d, 64);
            }
            if (lm == 0) { psum[q][row] = s; psq[q][row] = ss; }
        }
    }
    __syncthreads();
    if (tid < 32) {
        float a = 0.f, b = 0.f;
#pragma unroll
        for (int qq = 0; qq < 4; ++qq) { a += psum[qq][tid]; b += psq[qq][tid]; }
        float mu2 = a * (1.f / 256.f);
        float var = b * (1.f / 256.f) - mu2 * mu2;
        stat[0][tid] = mu2;
        stat[1][tid] = rsqrtf(var + LN_EPS);
    }
    __syncthreads();
    float g2[4], be2[4];
#pragma unroll
    for (int cl = 0; cl < 4; ++cl) {
        int c = (q * 4 + cl) * 16 + lm;
        g2[cl] = ln2g[c];
        be2[cl] = ln2b[c];
    }
    float* obase = out + ((size_t)(n * 6400 + p0)) * 256;
#pragma unroll
    for (int m = 0; m < 2; ++m) {
#pragma unroll
        for (int j = 0; j < 4; ++j) {
            int row = m * 16 + lk * 4 + j;
            float mu2 = stat[0][row], r2 = stat[1][row];
#pragma unroll
            for (int cl = 0; cl < 4; ++cl) {
                int c = (q * 4 + cl) * 16 + lm;
                obase[(size_t)row * 256 + c] =
                    (oacc[m * 4 + cl][j] - mu2) * r2 * g2[cl] + be2[cl];
            }
        }
    }
}

extern "C" void kernel_launch(void* const* d_in, const int* in_sizes, int n_in,
                              void* d_out, int out_size, void* d_ws, size_t ws_size,
                              hipStream_t stream) {
    const float* weight = (const float*)d_in[0];   // [8,400,400]
    const float* feature = (const float*)d_in[1];  // [8,256,80,80]
    const float* ln1g = (const float*)d_in[2];
    const float* ln1b = (const float*)d_in[3];
    const float* W1 = (const float*)d_in[4];       // [1024,256]
    const float* b1 = (const float*)d_in[5];
    const float* W2 = (const float*)d_in[6];       // [256,1024]
    const float* b2 = (const float*)d_in[7];
    const float* ln2g = (const float*)d_in[8];
    const float* ln2b = (const float*)d_in[9];
    float* outp = (float*)d_out;

    float* fs = (float*)d_ws;                         // 819200 f32
    float* rbuf = fs + 819200;                        // 819200 f32
    bf8_t* W1f = (bf8_t*)(rbuf + 819200);             // 32768 frags (512 KB)
    bf8_t* W2f = W1f + 32768;                         // 32768 frags (512 KB)

    cvt_kernel<<<256, 256, 0, stream>>>(W1, W2, W1f, W2f);
    pool_kernel<<<2048, 256, 0, stream>>>(feature, fs);
    att_kernel<<<400, 256, 0, stream>>>(weight, fs, rbuf);
    main_kernel<<<1600, 256, 0, stream>>>(feature, rbuf, ln1g, ln1b, W1f, b1,
                                          W2f, b2, ln2g, ln2b, outp);
}